// Round 7
// baseline (681.853 us; speedup 1.0000x reference)
//
#include <hip/hip_runtime.h>

typedef __attribute__((ext_vector_type(8))) short bf16x8;
typedef __attribute__((ext_vector_type(4))) float f32x4;

#define KK 27
#define MM 50000
#define NV 100000
#define CC 64
#define EPSV 1e-5f
#define PPB 400

// Dekker-style f32 -> bf16 hi (truncate, exact residual) + bf16 lo (RNE).
__device__ inline void split2(float x, unsigned short& h, unsigned short& l) {
    const unsigned u  = __float_as_uint(x);
    const unsigned hb = u & 0xFFFF0000u;
    h = (unsigned short)(hb >> 16);
    const float r = x - __uint_as_float(hb);      // exact
    const unsigned v = __float_as_uint(r);
    l = (unsigned short)((v + 0x7FFFu + ((v >> 16) & 1u)) >> 16);
}

__device__ inline unsigned short rne_bf16(float x) {
    const unsigned u = __float_as_uint(x);
    return (unsigned short)((u + 0x7FFFu + ((u >> 16) & 1u)) >> 16);
}

// ---------------------------------------------------------------------------
// features f32 [N][64] -> P [N][128] ushort: [0..63] bf16-hi, [64..127] bf16-lo
// ---------------------------------------------------------------------------
__global__ __launch_bounds__(256)
void split_planes(const float* __restrict__ x, unsigned short* __restrict__ P) {
    const int i = blockIdx.x * 256 + threadIdx.x;      // [0, NV*32)
    const int r = i >> 5, c2 = (i & 31) * 2;
    const float2 v = *(const float2*)(x + (size_t)r * CC + c2);
    unsigned short h0, l0, h1, l1;
    split2(v.x, h0, l0);
    split2(v.y, h1, l1);
    *(unsigned int*)(P + (size_t)r * 128 + c2)      = (unsigned)h0 | ((unsigned)h1 << 16);
    *(unsigned int*)(P + (size_t)r * 128 + 64 + c2) = (unsigned)l0 | ((unsigned)l1 << 16);
}

// ============================ CSR build (once) =============================
__global__ __launch_bounds__(256)
void csr_hist(const int* __restrict__ outm, int* __restrict__ cnt) {
    const int e = blockIdx.x * 256 + threadIdx.x;
    if (e < KK * MM) atomicAdd(&cnt[outm[e]], 1);
}

__global__ __launch_bounds__(1024)
void scan1(const int* __restrict__ cnt, int* __restrict__ off, int* __restrict__ bsum) {
    __shared__ int tmp[1024];
    const int t = threadIdx.x;
    const int i = blockIdx.x * 1024 + t;
    const int v = (i < NV) ? cnt[i] : 0;
    tmp[t] = v;
    __syncthreads();
    for (int d = 1; d < 1024; d <<= 1) {
        const int add = (t >= d) ? tmp[t - d] : 0;
        __syncthreads();
        tmp[t] += add;
        __syncthreads();
    }
    if (i < NV) off[i] = tmp[t] - v;        // exclusive within block
    if (t == 1023) bsum[blockIdx.x] = tmp[1023];
}

__global__ __launch_bounds__(128)
void scan2(int* __restrict__ bsum, int nb) {    // in-place exclusive, nb<=128
    __shared__ int tmp[128];
    const int t = threadIdx.x;
    const int v = (t < nb) ? bsum[t] : 0;
    tmp[t] = v;
    __syncthreads();
    for (int d = 1; d < 128; d <<= 1) {
        const int add = (t >= d) ? tmp[t - d] : 0;
        __syncthreads();
        tmp[t] += add;
        __syncthreads();
    }
    if (t < nb) bsum[t] = tmp[t] - v;
}

__global__ __launch_bounds__(256)
void scan3(int* __restrict__ off, const int* __restrict__ bsum) {
    const int i = blockIdx.x * 256 + threadIdx.x;
    if (i < NV) off[i] += bsum[i >> 10];
    if (i == 0) off[NV] = KK * MM;
}

__global__ __launch_bounds__(256)
void csr_fill(const int* __restrict__ outm, const int* __restrict__ off,
              int* __restrict__ cur, int* __restrict__ dst) {
    const int e = blockIdx.x * 256 + threadIdx.x;
    if (e >= KK * MM) return;
    const int row = outm[e];
    const int pos = atomicAdd(&cur[row], 1);
    dst[e] = off[row] + pos;
}

// ---------------------------------------------------------------------------
// MFMA GEMM, atomic-free: msgs[dst[e]] = bf16(f[inm[e]] @ W[k]).
// 2-deep A-frag prefetch pipeline; nontemporal msg stores (stream past cache
// so gathered P rows stay L2/L3-resident).
// ---------------------------------------------------------------------------
#define MF(a, b, c) c = __builtin_amdgcn_mfma_f32_16x16x32_bf16(a, b, c, 0, 0, 0)

struct AFrag { bf16x8 h0, h1, l0, l1; };

__device__ inline AFrag load_frag(const unsigned short* __restrict__ P,
                                  const int* __restrict__ inm, int base,
                                  int c16, int g) {
    const unsigned short* rp = P + (size_t)inm[base + c16] * 128 + g * 8;
    AFrag a;
    a.h0 = *(const bf16x8*)(rp);
    a.h1 = *(const bf16x8*)(rp + 32);
    a.l0 = *(const bf16x8*)(rp + 64);
    a.l1 = *(const bf16x8*)(rp + 96);
    return a;
}

__global__ __launch_bounds__(256)
void conv_gemm(const unsigned short* __restrict__ P, const float* __restrict__ W,
               const int* __restrict__ inm_all, const int* __restrict__ dst,
               unsigned short* __restrict__ msgs) {
    const int k   = blockIdx.y;
    const int L   = threadIdx.x & 63;
    const int wv  = threadIdx.x >> 6;
    const int g   = L >> 4;
    const int c16 = L & 15;

    __shared__ float lds[4352];

    {
        const float4* Wg  = (const float4*)(W + (size_t)k * CC * CC);
        float4*       Wl4 = (float4*)lds;
#pragma unroll
        for (int i = 0; i < 4; ++i)
            Wl4[threadIdx.x + 256 * i] = Wg[threadIdx.x + 256 * i];
    }
    __syncthreads();

    bf16x8 Wh[2][4], Wlo[2][4];
#pragma unroll
    for (int s = 0; s < 2; ++s)
#pragma unroll
        for (int t = 0; t < 4; ++t)
#pragma unroll
            for (int j = 0; j < 8; ++j) {
                const float w = lds[(g * 8 + j + 32 * s) * CC + 16 * t + c16];
                unsigned short h, lo;
                split2(w, h, lo);
                Wh[s][t][j]  = (short)h;
                Wlo[s][t][j] = (short)lo;
            }
    __syncthreads();

    float* ldsC = lds + wv * 1088;

    const int* inm = inm_all + (size_t)k * MM;
    const int pstart = blockIdx.x * PPB;
    const int pend   = min(MM, pstart + PPB);

    int b0 = pstart + wv * 16;
    if (b0 + 16 > pend) return;

    AFrag A0 = load_frag(P, inm, b0, c16, g);
    bool  v1 = (b0 + 80 <= pend);
    AFrag A1;
    if (v1) A1 = load_frag(P, inm, b0 + 64, c16, g);

    for (;;) {
        const bool v2 = (b0 + 144 <= pend);
        AFrag A2;
        if (v2) A2 = load_frag(P, inm, b0 + 128, c16, g);   // prefetch t+2

        f32x4 acc0 = {0.f, 0.f, 0.f, 0.f}, acc1 = acc0, acc2 = acc0, acc3 = acc0;
        MF(A0.h0, Wh[0][0], acc0); MF(A0.h0, Wh[0][1], acc1); MF(A0.h0, Wh[0][2], acc2); MF(A0.h0, Wh[0][3], acc3);
        MF(A0.h1, Wh[1][0], acc0); MF(A0.h1, Wh[1][1], acc1); MF(A0.h1, Wh[1][2], acc2); MF(A0.h1, Wh[1][3], acc3);
        MF(A0.l0, Wh[0][0], acc0); MF(A0.l0, Wh[0][1], acc1); MF(A0.l0, Wh[0][2], acc2); MF(A0.l0, Wh[0][3], acc3);
        MF(A0.l1, Wh[1][0], acc0); MF(A0.l1, Wh[1][1], acc1); MF(A0.l1, Wh[1][2], acc2); MF(A0.l1, Wh[1][3], acc3);
        MF(A0.h0, Wlo[0][0], acc0); MF(A0.h0, Wlo[0][1], acc1); MF(A0.h0, Wlo[0][2], acc2); MF(A0.h0, Wlo[0][3], acc3);
        MF(A0.h1, Wlo[1][0], acc0); MF(A0.h1, Wlo[1][1], acc1); MF(A0.h1, Wlo[1][2], acc2); MF(A0.h1, Wlo[1][3], acc3);

#pragma unroll
        for (int j = 0; j < 4; ++j) {
            ldsC[(g * 4 + j) * 68 +      c16] = acc0[j];
            ldsC[(g * 4 + j) * 68 + 16 + c16] = acc1[j];
            ldsC[(g * 4 + j) * 68 + 32 + c16] = acc2[j];
            ldsC[(g * 4 + j) * 68 + 48 + c16] = acc3[j];
        }
        const int e0 = k * MM + b0;
#pragma unroll
        for (int r = 0; r < 16; ++r) {
            const int d = dst[e0 + r];
            __builtin_nontemporal_store(rne_bf16(ldsC[r * 68 + L]),
                                        &msgs[(size_t)d * CC + L]);
        }

        if (!v1) break;
        A0 = A1; A1 = A2; v1 = v2; b0 += 64;
    }
}

// ---------------------------------------------------------------------------
// Gather-reduce: wave per output row; 16 lanes/msg (uint2 = 4 channels), so
// 4 msgs in flight per iteration; shfl_xor(16,32) finish; float4 write.
// ---------------------------------------------------------------------------
__global__ __launch_bounds__(256)
void csr_reduce(const unsigned short* __restrict__ msgs, const int* __restrict__ off,
                float* __restrict__ out) {
    const int L   = threadIdx.x & 63;
    const int wv  = threadIdx.x >> 6;
    const int n   = blockIdx.x * 4 + wv;
    if (n >= NV) return;
    const int q   = L & 15;
    const int sub = L >> 4;
    const int s = off[n], e = off[n + 1];
    float a0 = 0.f, a1 = 0.f, a2 = 0.f, a3 = 0.f;
    for (int i = s + sub; i < e; i += 4) {
        const uint2 v = *(const uint2*)(msgs + (size_t)i * CC + q * 4);
        a0 += __uint_as_float(v.x << 16);
        a1 += __uint_as_float(v.x & 0xFFFF0000u);
        a2 += __uint_as_float(v.y << 16);
        a3 += __uint_as_float(v.y & 0xFFFF0000u);
    }
    a0 += __shfl_xor(a0, 16); a1 += __shfl_xor(a1, 16);
    a2 += __shfl_xor(a2, 16); a3 += __shfl_xor(a3, 16);
    a0 += __shfl_xor(a0, 32); a1 += __shfl_xor(a1, 32);
    a2 += __shfl_xor(a2, 32); a3 += __shfl_xor(a3, 32);
    if (sub == 0) {
        const float4 r = {a0, a1, a2, a3};
        *(float4*)(out + (size_t)n * CC + q * 4) = r;
    }
}

// =============================== BN kernels ================================
__global__ __launch_bounds__(256)
void bn_stats(const float* __restrict__ x, float* __restrict__ stats) {
    const int c  = threadIdx.x & 63;
    const int rg = threadIdx.x >> 6;
    float s = 0.f, ss = 0.f;
    for (int r = blockIdx.x * 4 + rg; r < NV; r += gridDim.x * 4) {
        const float v = x[(size_t)r * CC + c];
        s += v;
        ss = fmaf(v, v, ss);
    }
    __shared__ float red[2][4][CC];
    red[0][rg][c] = s;
    red[1][rg][c] = ss;
    __syncthreads();
    if (threadIdx.x < CC) {
        const float ts  = red[0][0][c] + red[0][1][c] + red[0][2][c] + red[0][3][c];
        const float tss = red[1][0][c] + red[1][1][c] + red[1][2][c] + red[1][3][c];
        atomicAdd(&stats[c], ts);
        atomicAdd(&stats[CC + c], tss);
    }
}

__global__ __launch_bounds__(256)
void bn_relu_split(const float* __restrict__ x, const float* __restrict__ stats,
                   const float* __restrict__ gamma, const float* __restrict__ beta,
                   unsigned short* __restrict__ P) {
    const int i = blockIdx.x * 256 + threadIdx.x;
    const int r = i >> 5, c2 = (i & 31) * 2;
    float sc[2], sh[2];
#pragma unroll
    for (int j = 0; j < 2; ++j) {
        const int   c    = c2 + j;
        const float mu   = stats[c] * (1.f / NV);
        const float var  = fmaf(-mu, mu, stats[CC + c] * (1.f / NV));
        const float istd = rsqrtf(var + EPSV);
        sc[j] = gamma[c] * istd;
        sh[j] = fmaf(-mu, sc[j], beta[c]);
    }
    const float2 v = *(const float2*)(x + (size_t)r * CC + c2);
    const float y0 = fmaxf(fmaf(v.x, sc[0], sh[0]), 0.f);
    const float y1 = fmaxf(fmaf(v.y, sc[1], sh[1]), 0.f);
    unsigned short h0, l0, h1, l1;
    split2(y0, h0, l0);
    split2(y1, h1, l1);
    *(unsigned int*)(P + (size_t)r * 128 + c2)      = (unsigned)h0 | ((unsigned)h1 << 16);
    *(unsigned int*)(P + (size_t)r * 128 + 64 + c2) = (unsigned)l0 | ((unsigned)l1 << 16);
}

__global__ __launch_bounds__(256)
void bn_res_relu(float* __restrict__ x, const float* __restrict__ feat,
                 const float* __restrict__ stats,
                 const float* __restrict__ gamma, const float* __restrict__ beta) {
    const int tid   = blockIdx.x * blockDim.x + threadIdx.x;
    const int total = NV * CC / 4;
    const int cbase = (tid * 4) & (CC - 1);
    float scale[4], shift[4];
#pragma unroll
    for (int j = 0; j < 4; ++j) {
        const int   c    = cbase + j;
        const float mu   = stats[c] * (1.f / NV);
        const float var  = fmaf(-mu, mu, stats[CC + c] * (1.f / NV));
        const float istd = rsqrtf(var + EPSV);
        scale[j] = gamma[c] * istd;
        shift[j] = fmaf(-mu, scale[j], beta[c]);
    }
    float4*       x4 = (float4*)x;
    const float4* f4 = (const float4*)feat;
    for (int i = tid; i < total; i += gridDim.x * blockDim.x) {
        float4 v = x4[i];
        const float4 fr = f4[i];
        v.x = fmaxf(fmaf(v.x, scale[0], shift[0]) + fr.x, 0.f);
        v.y = fmaxf(fmaf(v.y, scale[1], shift[1]) + fr.y, 0.f);
        v.z = fmaxf(fmaf(v.z, scale[2], shift[2]) + fr.z, 0.f);
        v.w = fmaxf(fmaf(v.w, scale[3], shift[3]) + fr.w, 0.f);
        x4[i] = v;
    }
}

// ---------------------------------------------------------------------------
extern "C" void kernel_launch(void* const* d_in, const int* in_sizes, int n_in,
                              void* d_out, int out_size, void* d_ws, size_t ws_size,
                              hipStream_t stream) {
    const float* features = (const float*)d_in[0];
    const float* W1       = (const float*)d_in[1];
    const float* gamma1   = (const float*)d_in[2];
    const float* beta1    = (const float*)d_in[3];
    const float* W2       = (const float*)d_in[4];
    const float* gamma2   = (const float*)d_in[5];
    const float* beta2    = (const float*)d_in[6];
    const int*   in_maps  = (const int*)d_in[7];
    const int*   out_maps = (const int*)d_in[8];

    float* out = (float*)d_out;

    // ws layout
    unsigned short* P     = (unsigned short*)d_ws;           // NV*128 ushort
    float*          stats = (float*)(P + (size_t)NV * 128);  // 256 f32
    int*            cnt   = (int*)(stats + 256);             // NV
    int*            cur   = cnt + NV;                        // NV
    int*            off   = cur + NV;                        // NV+8
    int*            dst   = off + NV + 8;                    // KK*MM
    int*            bsum  = dst + KK * MM;                   // 256
    unsigned short* msgs  = (unsigned short*)(bsum + 256);   // KK*MM*64

    dim3 cgrid(MM / PPB, KK);                                // 125 x 27

    // zero stats + cnt + cur in one contiguous memset
    hipMemsetAsync(stats, 0, (256 + 2 * NV) * sizeof(int), stream);

    split_planes<<<12500, 256, 0, stream>>>(features, P);

    // CSR build (maps shared by both convs)
    csr_hist<<<(KK * MM + 255) / 256, 256, 0, stream>>>(out_maps, cnt);
    const int nb = (NV + 1023) / 1024;                       // 98
    scan1<<<nb, 1024, 0, stream>>>(cnt, off, bsum);
    scan2<<<1, 128, 0, stream>>>(bsum, nb);
    scan3<<<(NV + 255) / 256, 256, 0, stream>>>(off, bsum);
    csr_fill<<<(KK * MM + 255) / 256, 256, 0, stream>>>(out_maps, off, cur, dst);

    conv_gemm<<<cgrid, 256, 0, stream>>>(P, W1, in_maps, dst, msgs);
    csr_reduce<<<NV / 4, 256, 0, stream>>>(msgs, off, out);
    bn_stats<<<800, 256, 0, stream>>>(out, stats);
    bn_relu_split<<<12500, 256, 0, stream>>>(out, stats, gamma1, beta1, P);

    conv_gemm<<<cgrid, 256, 0, stream>>>(P, W2, in_maps, dst, msgs);
    csr_reduce<<<NV / 4, 256, 0, stream>>>(msgs, off, out);
    bn_stats<<<800, 256, 0, stream>>>(out, stats + 128);
    bn_res_relu<<<1024, 256, 0, stream>>>(out, features, stats + 128, gamma2, beta2);
}

// Round 8
// 599.553 us; speedup vs baseline: 1.1373x; 1.1373x over previous
//
#include <hip/hip_runtime.h>

typedef __attribute__((ext_vector_type(8))) short bf16x8;
typedef __attribute__((ext_vector_type(4))) float f32x4;

#define KK 27
#define MM 50000
#define NV 100000
#define CC 64
#define EPSV 1e-5f
#define PPB 400

// Dekker-style f32 -> bf16 hi (truncate, exact residual) + bf16 lo (RNE).
__device__ inline void split2(float x, unsigned short& h, unsigned short& l) {
    const unsigned u  = __float_as_uint(x);
    const unsigned hb = u & 0xFFFF0000u;
    h = (unsigned short)(hb >> 16);
    const float r = x - __uint_as_float(hb);      // exact
    const unsigned v = __float_as_uint(r);
    l = (unsigned short)((v + 0x7FFFu + ((v >> 16) & 1u)) >> 16);
}

__device__ inline unsigned short rne_bf16(float x) {
    const unsigned u = __float_as_uint(x);
    return (unsigned short)((u + 0x7FFFu + ((u >> 16) & 1u)) >> 16);
}

// ---------------------------------------------------------------------------
// features f32 [N][64] -> P [N][128] ushort: [0..63] bf16-hi, [64..127] bf16-lo
// ---------------------------------------------------------------------------
__global__ __launch_bounds__(256)
void split_planes(const float* __restrict__ x, unsigned short* __restrict__ P) {
    const int i = blockIdx.x * 256 + threadIdx.x;      // [0, NV*32)
    const int r = i >> 5, c2 = (i & 31) * 2;
    const float2 v = *(const float2*)(x + (size_t)r * CC + c2);
    unsigned short h0, l0, h1, l1;
    split2(v.x, h0, l0);
    split2(v.y, h1, l1);
    *(unsigned int*)(P + (size_t)r * 128 + c2)      = (unsigned)h0 | ((unsigned)h1 << 16);
    *(unsigned int*)(P + (size_t)r * 128 + 64 + c2) = (unsigned)l0 | ((unsigned)l1 << 16);
}

// ============================ CSR build (once) =============================
__global__ __launch_bounds__(256)
void csr_hist(const int* __restrict__ outm, int* __restrict__ cnt) {
    const int e = blockIdx.x * 256 + threadIdx.x;
    if (e < KK * MM) atomicAdd(&cnt[outm[e]], 1);
}

__global__ __launch_bounds__(1024)
void scan1(const int* __restrict__ cnt, int* __restrict__ off, int* __restrict__ bsum) {
    __shared__ int tmp[1024];
    const int t = threadIdx.x;
    const int i = blockIdx.x * 1024 + t;
    const int v = (i < NV) ? cnt[i] : 0;
    tmp[t] = v;
    __syncthreads();
    for (int d = 1; d < 1024; d <<= 1) {
        const int add = (t >= d) ? tmp[t - d] : 0;
        __syncthreads();
        tmp[t] += add;
        __syncthreads();
    }
    if (i < NV) off[i] = tmp[t] - v;        // exclusive within block
    if (t == 1023) bsum[blockIdx.x] = tmp[1023];
}

__global__ __launch_bounds__(128)
void scan2(int* __restrict__ bsum, int nb) {    // in-place exclusive, nb<=128
    __shared__ int tmp[128];
    const int t = threadIdx.x;
    const int v = (t < nb) ? bsum[t] : 0;
    tmp[t] = v;
    __syncthreads();
    for (int d = 1; d < 128; d <<= 1) {
        const int add = (t >= d) ? tmp[t - d] : 0;
        __syncthreads();
        tmp[t] += add;
        __syncthreads();
    }
    if (t < nb) bsum[t] = tmp[t] - v;
}

__global__ __launch_bounds__(256)
void scan3(int* __restrict__ off, const int* __restrict__ bsum) {
    const int i = blockIdx.x * 256 + threadIdx.x;
    if (i < NV) off[i] += bsum[i >> 10];
    if (i == 0) off[NV] = KK * MM;
}

__global__ __launch_bounds__(256)
void csr_fill(const int* __restrict__ outm, const int* __restrict__ off,
              int* __restrict__ cur, int* __restrict__ dst) {
    const int e = blockIdx.x * 256 + threadIdx.x;
    if (e >= KK * MM) return;
    const int row = outm[e];
    const int pos = atomicAdd(&cur[row], 1);
    dst[e] = off[row] + pos;
}

// ---------------------------------------------------------------------------
// MFMA GEMM, atomic-free: msgs[dst[e]] = bf16(f[inm[e]] @ W[k]).
// R6-proven form: 1-deep prefetch, launch_bounds(256,3) -> VGPR 64, occ ~36%.
// ---------------------------------------------------------------------------
#define MF(a, b, c) c = __builtin_amdgcn_mfma_f32_16x16x32_bf16(a, b, c, 0, 0, 0)

__global__ __launch_bounds__(256, 3)
void conv_gemm(const unsigned short* __restrict__ P, const float* __restrict__ W,
               const int* __restrict__ inm_all, const int* __restrict__ dst,
               unsigned short* __restrict__ msgs) {
    const int k   = blockIdx.y;
    const int L   = threadIdx.x & 63;
    const int wv  = threadIdx.x >> 6;
    const int g   = L >> 4;
    const int c16 = L & 15;

    __shared__ float lds[4352];

    {
        const float4* Wg  = (const float4*)(W + (size_t)k * CC * CC);
        float4*       Wl4 = (float4*)lds;
#pragma unroll
        for (int i = 0; i < 4; ++i)
            Wl4[threadIdx.x + 256 * i] = Wg[threadIdx.x + 256 * i];
    }
    __syncthreads();

    bf16x8 Wh[2][4], Wlo[2][4];
#pragma unroll
    for (int s = 0; s < 2; ++s)
#pragma unroll
        for (int t = 0; t < 4; ++t)
#pragma unroll
            for (int j = 0; j < 8; ++j) {
                const float w = lds[(g * 8 + j + 32 * s) * CC + 16 * t + c16];
                unsigned short h, lo;
                split2(w, h, lo);
                Wh[s][t][j]  = (short)h;
                Wlo[s][t][j] = (short)lo;
            }
    __syncthreads();

    float* ldsC = lds + wv * 1088;

    const int* inm = inm_all + (size_t)k * MM;
    const int pstart = blockIdx.x * PPB;
    const int pend   = min(MM, pstart + PPB);

    int base = pstart + wv * 16;
    if (base + 16 > pend) return;

    const unsigned short* rp = P + (size_t)inm[base + c16] * 128;
    bf16x8 ah0 = *(const bf16x8*)(rp +      g * 8);
    bf16x8 ah1 = *(const bf16x8*)(rp + 32 + g * 8);
    bf16x8 al0 = *(const bf16x8*)(rp + 64 + g * 8);
    bf16x8 al1 = *(const bf16x8*)(rp + 96 + g * 8);

    while (true) {
        const int  nbase = base + 64;
        const bool hasn  = (nbase + 16 <= pend);
        bf16x8 nh0, nh1, nl0, nl1;
        if (hasn) {
            const unsigned short* np = P + (size_t)inm[nbase + c16] * 128;
            nh0 = *(const bf16x8*)(np +      g * 8);
            nh1 = *(const bf16x8*)(np + 32 + g * 8);
            nl0 = *(const bf16x8*)(np + 64 + g * 8);
            nl1 = *(const bf16x8*)(np + 96 + g * 8);
        }

        f32x4 acc0 = {0.f, 0.f, 0.f, 0.f}, acc1 = acc0, acc2 = acc0, acc3 = acc0;
        MF(ah0, Wh[0][0], acc0); MF(ah0, Wh[0][1], acc1); MF(ah0, Wh[0][2], acc2); MF(ah0, Wh[0][3], acc3);
        MF(ah1, Wh[1][0], acc0); MF(ah1, Wh[1][1], acc1); MF(ah1, Wh[1][2], acc2); MF(ah1, Wh[1][3], acc3);
        MF(al0, Wh[0][0], acc0); MF(al0, Wh[0][1], acc1); MF(al0, Wh[0][2], acc2); MF(al0, Wh[0][3], acc3);
        MF(al1, Wh[1][0], acc0); MF(al1, Wh[1][1], acc1); MF(al1, Wh[1][2], acc2); MF(al1, Wh[1][3], acc3);
        MF(ah0, Wlo[0][0], acc0); MF(ah0, Wlo[0][1], acc1); MF(ah0, Wlo[0][2], acc2); MF(ah0, Wlo[0][3], acc3);
        MF(ah1, Wlo[1][0], acc0); MF(ah1, Wlo[1][1], acc1); MF(ah1, Wlo[1][2], acc2); MF(ah1, Wlo[1][3], acc3);

#pragma unroll
        for (int j = 0; j < 4; ++j) {
            ldsC[(g * 4 + j) * 68 +      c16] = acc0[j];
            ldsC[(g * 4 + j) * 68 + 16 + c16] = acc1[j];
            ldsC[(g * 4 + j) * 68 + 32 + c16] = acc2[j];
            ldsC[(g * 4 + j) * 68 + 48 + c16] = acc3[j];
        }
        const int e0 = k * MM + base;
#pragma unroll
        for (int r = 0; r < 16; ++r) {
            const int d = dst[e0 + r];
            msgs[(size_t)d * CC + L] = rne_bf16(ldsC[r * 68 + L]);  // 128B plain store
        }

        if (!hasn) break;
        base = nbase;
        ah0 = nh0; ah1 = nh1; al0 = nl0; al1 = nl1;
    }
}

// ---------------------------------------------------------------------------
// Fused gather-reduce + BN stats: grid-stride over rows (wave per row),
// 16 lanes/msg (uint2 = 4 ch), shfl finish, f32x4 row write; per-thread
// sum/ssq accumulated across rows, block-reduced, 128 atomics per block.
// ---------------------------------------------------------------------------
__global__ __launch_bounds__(256)
void csr_reduce_stats(const unsigned short* __restrict__ msgs,
                      const int* __restrict__ off,
                      float* __restrict__ out, float* __restrict__ stats) {
    const int L   = threadIdx.x & 63;
    const int wv  = threadIdx.x >> 6;
    const int q   = L & 15;
    const int sub = L >> 4;

    float sum0 = 0.f, sum1 = 0.f, sum2 = 0.f, sum3 = 0.f;
    float ssq0 = 0.f, ssq1 = 0.f, ssq2 = 0.f, ssq3 = 0.f;

    for (int n = blockIdx.x * 4 + wv; n < NV; n += gridDim.x * 4) {
        const int s = off[n], e = off[n + 1];
        float a0 = 0.f, a1 = 0.f, a2 = 0.f, a3 = 0.f;
        for (int i = s + sub; i < e; i += 4) {
            const uint2 v = *(const uint2*)(msgs + (size_t)i * CC + q * 4);
            a0 += __uint_as_float(v.x << 16);
            a1 += __uint_as_float(v.x & 0xFFFF0000u);
            a2 += __uint_as_float(v.y << 16);
            a3 += __uint_as_float(v.y & 0xFFFF0000u);
        }
        a0 += __shfl_xor(a0, 16); a1 += __shfl_xor(a1, 16);
        a2 += __shfl_xor(a2, 16); a3 += __shfl_xor(a3, 16);
        a0 += __shfl_xor(a0, 32); a1 += __shfl_xor(a1, 32);
        a2 += __shfl_xor(a2, 32); a3 += __shfl_xor(a3, 32);
        if (sub == 0) {
            const float4 r = {a0, a1, a2, a3};
            *(float4*)(out + (size_t)n * CC + q * 4) = r;
            sum0 += a0; ssq0 = fmaf(a0, a0, ssq0);
            sum1 += a1; ssq1 = fmaf(a1, a1, ssq1);
            sum2 += a2; ssq2 = fmaf(a2, a2, ssq2);
            sum3 += a3; ssq3 = fmaf(a3, a3, ssq3);
        }
    }

    __shared__ float red[2][4][CC];
    if (sub == 0) {
        red[0][wv][q * 4 + 0] = sum0; red[1][wv][q * 4 + 0] = ssq0;
        red[0][wv][q * 4 + 1] = sum1; red[1][wv][q * 4 + 1] = ssq1;
        red[0][wv][q * 4 + 2] = sum2; red[1][wv][q * 4 + 2] = ssq2;
        red[0][wv][q * 4 + 3] = sum3; red[1][wv][q * 4 + 3] = ssq3;
    }
    __syncthreads();
    if (threadIdx.x < CC) {
        const int c = threadIdx.x;
        const float ts  = red[0][0][c] + red[0][1][c] + red[0][2][c] + red[0][3][c];
        const float tss = red[1][0][c] + red[1][1][c] + red[1][2][c] + red[1][3][c];
        atomicAdd(&stats[c], ts);
        atomicAdd(&stats[CC + c], tss);
    }
}

// =============================== BN kernels ================================
__global__ __launch_bounds__(256)
void bn_relu_split(const float* __restrict__ x, const float* __restrict__ stats,
                   const float* __restrict__ gamma, const float* __restrict__ beta,
                   unsigned short* __restrict__ P) {
    const int i = blockIdx.x * 256 + threadIdx.x;
    const int r = i >> 5, c2 = (i & 31) * 2;
    float sc[2], sh[2];
#pragma unroll
    for (int j = 0; j < 2; ++j) {
        const int   c    = c2 + j;
        const float mu   = stats[c] * (1.f / NV);
        const float var  = fmaf(-mu, mu, stats[CC + c] * (1.f / NV));
        const float istd = rsqrtf(var + EPSV);
        sc[j] = gamma[c] * istd;
        sh[j] = fmaf(-mu, sc[j], beta[c]);
    }
    const float2 v = *(const float2*)(x + (size_t)r * CC + c2);
    const float y0 = fmaxf(fmaf(v.x, sc[0], sh[0]), 0.f);
    const float y1 = fmaxf(fmaf(v.y, sc[1], sh[1]), 0.f);
    unsigned short h0, l0, h1, l1;
    split2(y0, h0, l0);
    split2(y1, h1, l1);
    *(unsigned int*)(P + (size_t)r * 128 + c2)      = (unsigned)h0 | ((unsigned)h1 << 16);
    *(unsigned int*)(P + (size_t)r * 128 + 64 + c2) = (unsigned)l0 | ((unsigned)l1 << 16);
}

__global__ __launch_bounds__(256)
void bn_res_relu(float* __restrict__ x, const float* __restrict__ feat,
                 const float* __restrict__ stats,
                 const float* __restrict__ gamma, const float* __restrict__ beta) {
    const int tid   = blockIdx.x * blockDim.x + threadIdx.x;
    const int total = NV * CC / 4;
    const int cbase = (tid * 4) & (CC - 1);
    float scale[4], shift[4];
#pragma unroll
    for (int j = 0; j < 4; ++j) {
        const int   c    = cbase + j;
        const float mu   = stats[c] * (1.f / NV);
        const float var  = fmaf(-mu, mu, stats[CC + c] * (1.f / NV));
        const float istd = rsqrtf(var + EPSV);
        scale[j] = gamma[c] * istd;
        shift[j] = fmaf(-mu, scale[j], beta[c]);
    }
    float4*       x4 = (float4*)x;
    const float4* f4 = (const float4*)feat;
    for (int i = tid; i < total; i += gridDim.x * blockDim.x) {
        float4 v = x4[i];
        const float4 fr = f4[i];
        v.x = fmaxf(fmaf(v.x, scale[0], shift[0]) + fr.x, 0.f);
        v.y = fmaxf(fmaf(v.y, scale[1], shift[1]) + fr.y, 0.f);
        v.z = fmaxf(fmaf(v.z, scale[2], shift[2]) + fr.z, 0.f);
        v.w = fmaxf(fmaf(v.w, scale[3], shift[3]) + fr.w, 0.f);
        x4[i] = v;
    }
}

// ---------------------------------------------------------------------------
extern "C" void kernel_launch(void* const* d_in, const int* in_sizes, int n_in,
                              void* d_out, int out_size, void* d_ws, size_t ws_size,
                              hipStream_t stream) {
    const float* features = (const float*)d_in[0];
    const float* W1       = (const float*)d_in[1];
    const float* gamma1   = (const float*)d_in[2];
    const float* beta1    = (const float*)d_in[3];
    const float* W2       = (const float*)d_in[4];
    const float* gamma2   = (const float*)d_in[5];
    const float* beta2    = (const float*)d_in[6];
    const int*   in_maps  = (const int*)d_in[7];
    const int*   out_maps = (const int*)d_in[8];

    float* out = (float*)d_out;

    // ws layout
    unsigned short* P     = (unsigned short*)d_ws;           // NV*128 ushort
    float*          stats = (float*)(P + (size_t)NV * 128);  // 256 f32
    int*            cnt   = (int*)(stats + 256);             // NV
    int*            cur   = cnt + NV;                        // NV
    int*            off   = cur + NV;                        // NV+8
    int*            dst   = off + NV + 8;                    // KK*MM
    int*            bsum  = dst + KK * MM;                   // 256
    unsigned short* msgs  = (unsigned short*)(bsum + 256);   // KK*MM*64

    dim3 cgrid(MM / PPB, KK);                                // 125 x 27

    // zero stats + cnt + cur in one contiguous memset
    hipMemsetAsync(stats, 0, (256 + 2 * NV) * sizeof(int), stream);

    split_planes<<<12500, 256, 0, stream>>>(features, P);

    // CSR build (maps shared by both convs)
    csr_hist<<<(KK * MM + 255) / 256, 256, 0, stream>>>(out_maps, cnt);
    const int nb = (NV + 1023) / 1024;                       // 98
    scan1<<<nb, 1024, 0, stream>>>(cnt, off, bsum);
    scan2<<<1, 128, 0, stream>>>(bsum, nb);
    scan3<<<(NV + 255) / 256, 256, 0, stream>>>(off, bsum);
    csr_fill<<<(KK * MM + 255) / 256, 256, 0, stream>>>(out_maps, off, cur, dst);

    conv_gemm<<<cgrid, 256, 0, stream>>>(P, W1, in_maps, dst, msgs);
    csr_reduce_stats<<<2048, 256, 0, stream>>>(msgs, off, out, stats);
    bn_relu_split<<<12500, 256, 0, stream>>>(out, stats, gamma1, beta1, P);

    conv_gemm<<<cgrid, 256, 0, stream>>>(P, W2, in_maps, dst, msgs);
    csr_reduce_stats<<<2048, 256, 0, stream>>>(msgs, off, out, stats + 128);
    bn_res_relu<<<1024, 256, 0, stream>>>(out, features, stats + 128, gamma2, beta2);
}